// Round 9
// baseline (1433.218 us; speedup 1.0000x reference)
//
#include <hip/hip_runtime.h>

typedef _Float16 half2_t __attribute__((ext_vector_type(2)));
typedef unsigned int u32;

#define NW 252   // total windows: 1 initial + 3 warmup + 248 autoregressive

__device__ inline u32 pk(float x, float y) {
  half2_t h; h.x = (_Float16)x; h.y = (_Float16)y;
  return __builtin_bit_cast(u32, h);
}

__device__ inline float fdot2(u32 a, u32 b, float c) {
#if __has_builtin(__builtin_amdgcn_fdot2)
  return __builtin_amdgcn_fdot2(__builtin_bit_cast(half2_t, a),
                                __builtin_bit_cast(half2_t, b), c, false);
#else
  half2_t ah = __builtin_bit_cast(half2_t, a);
  half2_t bh = __builtin_bit_cast(half2_t, b);
  return c + (float)ah.x * (float)bh.x + (float)ah.y * (float)bh.y;
#endif
}

__device__ inline float fast_rcp(float x) {
#if __has_builtin(__builtin_amdgcn_rcpf)
  return __builtin_amdgcn_rcpf(x);
#else
  return 1.0f / x;
#endif
}

__device__ inline float sigf(float x)  { return fast_rcp(1.0f + __expf(-x)); }
__device__ inline float tanh_(float x) { return 1.0f - 2.0f * fast_rcp(__expf(2.0f * x) + 1.0f); }

// butterfly sum over the 4 lanes of a quad (ks = tid&3) via DPP quad_perm
__device__ inline float quad_reduce(float v) {
  int x = __builtin_bit_cast(int, v);
  int y = __builtin_amdgcn_update_dpp(0, x, 0xB1, 0xF, 0xF, true); // xor1
  v += __builtin_bit_cast(float, y);
  x = __builtin_bit_cast(int, v);
  y = __builtin_amdgcn_update_dpp(0, x, 0x4E, 0xF, 0xF, true);     // xor2
  v += __builtin_bit_cast(float, y);
  return v;
}

// pack 8 consecutive f32 -> 4 f16x2 words
__device__ inline uint4 pk8(const float* p) {
  const float4* s = (const float4*)p;
  float4 a = s[0], b = s[1];
  return make_uint4(pk(a.x, a.y), pk(a.z, a.w), pk(b.x, b.y), pk(b.z, b.w));
}

// 16 dots: 4 gates x 4 k-pair words
#define DOTQ(sq, g0_, g1_, g2_, g3_) {                                     \
    acc0 = fdot2(g0_.x, sq.x, acc0); acc0 = fdot2(g0_.y, sq.y, acc0);      \
    acc0 = fdot2(g0_.z, sq.z, acc0); acc0 = fdot2(g0_.w, sq.w, acc0);      \
    acc1 = fdot2(g1_.x, sq.x, acc1); acc1 = fdot2(g1_.y, sq.y, acc1);      \
    acc1 = fdot2(g1_.z, sq.z, acc1); acc1 = fdot2(g1_.w, sq.w, acc1);      \
    acc2 = fdot2(g2_.x, sq.x, acc2); acc2 = fdot2(g2_.y, sq.y, acc2);      \
    acc2 = fdot2(g2_.z, sq.z, acc2); acc2 = fdot2(g2_.w, sq.w, acc2);      \
    acc3 = fdot2(g3_.x, sq.x, acc3); acc3 = fdot2(g3_.y, sq.y, acc3);      \
    acc3 = fdot2(g3_.z, sq.z, acc3); acc3 = fdot2(g3_.w, sq.w, acc3); }

// ---- R8/R9 design: live WITHIN the 128-VGPR/thread wall (R0-R7: unbreakable).
// Weights (96K words/block) split across three fast homes:
//   wA (Whh0)  -> 64 words/thread in registers (fits: ~110 peak demand)
//   wC (Whh1)  -> 128KB f16 in LDS (conflict-free lane-contiguous b128)
//   wB (Wih1)  -> streamed per stage from d_ws (f16-prepacked; SHARED by all
//                 128 blocks -> 384KB unique, pure L2 hits; the old scratch
//                 spill privatized this into 48MB -> the L2 thrash we saw)
// R8 run was an infra flake ("container failed twice") -- resubmitted as-is.

// wB stream chunk: 4 gates x 1 k-chunk, then 16 dots
#define WBCHUNK(kq_, sq_) {                                                \
    uint4 g0_, g1_, g2_, g3_;                                              \
    if constexpr (WSMODE) {                                                \
      g0_ = ws[(0*4+(kq_))*512 + tid]; g1_ = ws[(1*4+(kq_))*512 + tid];    \
      g2_ = ws[(2*4+(kq_))*512 + tid]; g3_ = ws[(3*4+(kq_))*512 + tid];    \
    } else {                                                               \
      g0_ = pk8(Wih1 + (0*128+j)*128 + ks*32 + (kq_)*8);                   \
      g1_ = pk8(Wih1 + (1*128+j)*128 + ks*32 + (kq_)*8);                   \
      g2_ = pk8(Wih1 + (2*128+j)*128 + ks*32 + (kq_)*8);                   \
      g3_ = pk8(Wih1 + (3*128+j)*128 + ks*32 + (kq_)*8);                   \
    }                                                                      \
    DOTQ(sq_, g0_, g1_, g2_, g3_); }

// wC LDS chunk
#define WCCHUNK(kq_, sq_) {                                                \
    uint4 e0_ = wCl[(0*4+(kq_))*512 + tid];                                \
    uint4 e1_ = wCl[(1*4+(kq_))*512 + tid];                                \
    uint4 e2_ = wCl[(2*4+(kq_))*512 + tid];                                \
    uint4 e3_ = wCl[(3*4+(kq_))*512 + tid];                                \
    DOTQ(sq_, e0_, e1_, e2_, e3_); }

#define L0STEP(w_, t_, p_) {                                               \
    float x0, x1, x2;                                                      \
    if ((w_) < 4) {                                                        \
      if ((w_) == 0 || (t_) < 3) {                                         \
        const float* r_ = &trajS[((w_) + (t_)) * 3];                       \
        x0 = r_[0]; x1 = r_[1]; x2 = r_[2];                                \
      } else {                       /* warmup last row: [ctrl, p_{w-1}] */ \
        x0 = trajS[(4 + (w_)) * 3];                                        \
        x1 = preds[((w_) - 1) * 2];                                        \
        x2 = preds[((w_) - 1) * 2 + 1];                                    \
      }                                                                    \
    } else {                         /* AR: [p0, p1, ctrl] */              \
      const int s_ = (w_) - 4;                                             \
      x0 = preds[(s_ + (t_)) * 2];                                         \
      x1 = preds[(s_ + (t_)) * 2 + 1];                                     \
      x2 = trajS[((w_) + (t_)) * 3];                                       \
    }                                                                      \
    float acc0 = 0.f, acc1 = 0.f, acc2 = 0.f, acc3 = 0.f;                  \
    if (ks == 0) {                   /* bias+Wih0 from LDS tables */       \
      float4 q0_ = ldsG0[j*4+0], q1_ = ldsG0[j*4+1];                       \
      float4 q2_ = ldsG0[j*4+2], q3_ = ldsG0[j*4+3];                       \
      acc0 = q0_.w + q0_.x*x0 + q0_.y*x1 + q0_.z*x2;                       \
      acc1 = q1_.w + q1_.x*x0 + q1_.y*x1 + q1_.z*x2;                       \
      acc2 = q2_.w + q2_.x*x0 + q2_.y*x1 + q2_.z*x2;                       \
      acc3 = q3_.w + q3_.x*x0 + q3_.y*x1 + q3_.z*x2;                       \
    }                                                                      \
    if ((t_) > 0) {                                                        \
      const uint4* hb_ = (const uint4*)(h0buf[p_]) + ks*4;                 \
      uint4 s0_ = hb_[0], s1_ = hb_[1], s2_ = hb_[2], s3_ = hb_[3];        \
      DOTQ(s0_, A0q0, A1q0, A2q0, A3q0);                                   \
      DOTQ(s1_, A0q1, A1q1, A2q1, A3q1);                                   \
      DOTQ(s2_, A0q2, A1q2, A2q2, A3q2);                                   \
      DOTQ(s3_, A0q3, A1q3, A2q3, A3q3);                                   \
    }                                                                      \
    acc0 = quad_reduce(acc0); acc1 = quad_reduce(acc1);                    \
    acc2 = quad_reduce(acc2); acc3 = quad_reduce(acc3);                    \
    float ig_ = sigf(acc0), fg_ = sigf(acc1);                              \
    float gg_ = tanh_(acc2), og_ = sigf(acc3);                             \
    float cp_ = (t_) ? c0 : 0.f;                                           \
    c0  = fg_ * cp_ + ig_ * gg_;                                           \
    h0f = og_ * tanh_(c0);                                                 \
    if (ks == 0) h0buf[(p_) ^ 1][j] = (_Float16)h0f;                       \
  }

#define L1STEP(t_, p_) {                                                   \
    float acc0 = 0.f, acc1 = 0.f, acc2 = 0.f, acc3 = 0.f;                  \
    if (ks == 0) { float4 bv_ = ldsB1[j];                                  \
      acc0 = bv_.x; acc1 = bv_.y; acc2 = bv_.z; acc3 = bv_.w; }            \
    {                                                                      \
      const uint4* hb_ = (const uint4*)(h0buf[p_]) + ks*4;                 \
      uint4 s0_ = hb_[0], s1_ = hb_[1], s2_ = hb_[2], s3_ = hb_[3];        \
      WBCHUNK(0, s0_); WBCHUNK(1, s1_);                                    \
      WBCHUNK(2, s2_); WBCHUNK(3, s3_);                                    \
    }                                                                      \
    if ((t_) > 0) {                                                        \
      const uint4* hc_ = (const uint4*)(h1buf[p_]) + ks*4;                 \
      uint4 r0_ = hc_[0], r1_ = hc_[1], r2_ = hc_[2], r3_ = hc_[3];        \
      WCCHUNK(0, r0_); WCCHUNK(1, r1_);                                    \
      WCCHUNK(2, r2_); WCCHUNK(3, r3_);                                    \
    }                                                                      \
    acc0 = quad_reduce(acc0); acc1 = quad_reduce(acc1);                    \
    acc2 = quad_reduce(acc2); acc3 = quad_reduce(acc3);                    \
    float ig_ = sigf(acc0), fg_ = sigf(acc1);                              \
    float gg_ = tanh_(acc2), og_ = sigf(acc3);                             \
    float cp_ = (t_) ? c1 : 0.f;                                           \
    c1  = fg_ * cp_ + ig_ * gg_;                                           \
    h1f = og_ * tanh_(c1);                                                 \
    if (ks == 0) {                                                         \
      h1buf[(p_) ^ 1][j] = (_Float16)h1f;                                  \
      if ((t_) == 3) sh_h1f[j] = h1f;  /* f32 copy for the head */         \
    }                                                                      \
  }

#define HD(w_) {                                                           \
    if (tid < 8) {                                                         \
      const int d_ = tid >> 2;         /* ks = tid&3 splits K */           \
      const float* wrow_ = &sh_Wl[d_ * 128 + ks * 32];                     \
      const float* hrow_ = &sh_h1f[ks * 32];                               \
      float s_ = 0.f;                                                      \
      _Pragma("unroll")                                                    \
      for (int m = 0; m < 32; ++m) s_ = fmaf(wrow_[m], hrow_[m], s_);      \
      s_ = quad_reduce(s_);                                                \
      if (ks == 0) {                                                       \
        float base_ = ((w_) < 4) ? trajS[(3 + (w_)) * 3 + 1 + d_]          \
                                 : preds[((w_) - 1) * 2 + d_];             \
        preds[(w_) * 2 + d_] = base_ + s_ + blv;                           \
      }                                                                    \
    }                                                                      \
  }

// prepack Wih1 f32 -> f16x2 chunk layout in workspace (run once per launch,
// stream-ordered before the main kernel). Layout: entry e = (g*4+kq)*512+t.
__global__ void wb_prepack(const float* __restrict__ Wih1, uint4* __restrict__ ws) {
  const int e = blockIdx.x * blockDim.x + threadIdx.x;
  if (e >= 8192) return;
  const int t = e & 511, q = e >> 9;
  const int g = q >> 2, kq = q & 3, j = t >> 2, ks = t & 3;
  ws[e] = pk8(Wih1 + (g * 128 + j) * 128 + ks * 32 + kq * 8);
}

// 512 threads (8 waves), one block per CU (grid=128 on 256 CUs).
template <int WSMODE>
__global__ __launch_bounds__(512) void lstm_roll(
    const float* __restrict__ traj,
    const float* __restrict__ Wih0, const float* __restrict__ Whh0,
    const float* __restrict__ bih0, const float* __restrict__ bhh0,
    const float* __restrict__ Wih1, const float* __restrict__ Whh1,
    const float* __restrict__ bih1, const float* __restrict__ bhh1,
    const float* __restrict__ Wl,   const float* __restrict__ bl,
    const uint4* __restrict__ ws,
    float* __restrict__ out)
{
  const int b   = blockIdx.x;
  const int B   = gridDim.x;
  const int tid = threadIdx.x;
  const int j   = tid >> 2;   // hidden index 0..127
  const int ks  = tid & 3;    // k-slice 0..3 (32 k's each)

  __shared__ __align__(16) _Float16 h0buf[2][128];  // parity ping-pong
  __shared__ __align__(16) _Float16 h1buf[2][128];
  __shared__ float sh_h1f[128];      // f32 h1[3] for the head
  __shared__ float sh_Wl[256];
  __shared__ float trajS[256 * 3];
  __shared__ float preds[NW * 2];
  __shared__ float4 ldsG0[512];      // per (j,g): {Wih0 row, bias0}
  __shared__ float4 ldsB1[128];      // per j: bias1 for 4 gates
  __shared__ uint4  wCl[8192];       // Whh1, f16x2, 128KB, chunk layout

  for (int i = tid; i < 768; i += 512) trajS[i] = traj[b * 768 + i];
  if (tid < 256) sh_Wl[tid] = Wl[tid];
  float blv = 0.0f;
  if (tid < 8) blv = bl[tid >> 2];

  if (tid < 128) {                   // bias / Wih0 tables
    const int jj = tid;
#pragma unroll
    for (int g = 0; g < 4; ++g) {
      const int row = g * 128 + jj;
      ldsG0[jj * 4 + g] = make_float4(Wih0[row * 3 + 0], Wih0[row * 3 + 1],
                                      Wih0[row * 3 + 2], bih0[row] + bhh0[row]);
    }
    ldsB1[jj] = make_float4(bih1[0 * 128 + jj] + bhh1[0 * 128 + jj],
                            bih1[1 * 128 + jj] + bhh1[1 * 128 + jj],
                            bih1[2 * 128 + jj] + bhh1[2 * 128 + jj],
                            bih1[3 * 128 + jj] + bhh1[3 * 128 + jj]);
  }

  // wC (Whh1) -> LDS, f16-packed, chunk layout (lane-contiguous b128 reads)
#pragma unroll
  for (int q = 0; q < 16; ++q) {
    const int g = q >> 2, kq = q & 3;
    wCl[q * 512 + tid] = pk8(Whh1 + (g * 128 + j) * 128 + ks * 32 + kq * 8);
  }

  // wA (Whh0) -> registers: 16 named uint4 (gate g, k-chunk kq)
  uint4 A0q0 = pk8(Whh0 + (0*128+j)*128 + ks*32 + 0*8);
  uint4 A0q1 = pk8(Whh0 + (0*128+j)*128 + ks*32 + 1*8);
  uint4 A0q2 = pk8(Whh0 + (0*128+j)*128 + ks*32 + 2*8);
  uint4 A0q3 = pk8(Whh0 + (0*128+j)*128 + ks*32 + 3*8);
  uint4 A1q0 = pk8(Whh0 + (1*128+j)*128 + ks*32 + 0*8);
  uint4 A1q1 = pk8(Whh0 + (1*128+j)*128 + ks*32 + 1*8);
  uint4 A1q2 = pk8(Whh0 + (1*128+j)*128 + ks*32 + 2*8);
  uint4 A1q3 = pk8(Whh0 + (1*128+j)*128 + ks*32 + 3*8);
  uint4 A2q0 = pk8(Whh0 + (2*128+j)*128 + ks*32 + 0*8);
  uint4 A2q1 = pk8(Whh0 + (2*128+j)*128 + ks*32 + 1*8);
  uint4 A2q2 = pk8(Whh0 + (2*128+j)*128 + ks*32 + 2*8);
  uint4 A2q3 = pk8(Whh0 + (2*128+j)*128 + ks*32 + 3*8);
  uint4 A3q0 = pk8(Whh0 + (3*128+j)*128 + ks*32 + 0*8);
  uint4 A3q1 = pk8(Whh0 + (3*128+j)*128 + ks*32 + 1*8);
  uint4 A3q2 = pk8(Whh0 + (3*128+j)*128 + ks*32 + 2*8);
  uint4 A3q3 = pk8(Whh0 + (3*128+j)*128 + ks*32 + 3*8);

  float c0 = 0.f, c1 = 0.f, h0f = 0.f, h1f = 0.f;

  __syncthreads();

  int p = 0;
  // prologue: L0[0] of window 0 (no h-dependency)
  L0STEP(0, 0, p);
  __syncthreads(); p ^= 1;

#pragma unroll 1
  for (int w = 0; w < NW; ++w) {
    // s0: head(w-1) || L0[1](w) || L1[0](w)
    if (w > 0) HD(w - 1);
    L0STEP(w, 1, p);
    L1STEP(0, p);
    __syncthreads(); p ^= 1;
    // s1: L0[2](w) || L1[1](w)
    L0STEP(w, 2, p);
    L1STEP(1, p);
    __syncthreads(); p ^= 1;
    // s2: L0[3](w) || L1[2](w)   (preds[w-1] ready since s0)
    L0STEP(w, 3, p);
    L1STEP(2, p);
    __syncthreads(); p ^= 1;
    // s3: L1[3](w) || L0[0](w+1)
    L1STEP(3, p);
    if (w < NW - 1) L0STEP(w + 1, 0, p);
    __syncthreads(); p ^= 1;
  }

  // epilogue: head of the last window
  HD(NW - 1);
  __syncthreads();

  // ================= outputs =================
  for (int i = tid; i < NW * 2; i += 512) out[b * (NW * 2) + i] = preds[i];
  if (ks == 0) {
    const int oh = B * NW * 2;
    const int oc = oh + 2 * B * 128;
    out[oh +            b * 128 + j] = h0f;
    out[oh + B * 128 +  b * 128 + j] = h1f;
    out[oc +            b * 128 + j] = c0;
    out[oc + B * 128 +  b * 128 + j] = c1;
  }
}

extern "C" void kernel_launch(void* const* d_in, const int* in_sizes, int n_in,
                              void* d_out, int out_size, void* d_ws, size_t ws_size,
                              hipStream_t stream) {
  const float* traj = (const float*)d_in[0];
  const float* Wih0 = (const float*)d_in[1];
  const float* Whh0 = (const float*)d_in[2];
  const float* bih0 = (const float*)d_in[3];
  const float* bhh0 = (const float*)d_in[4];
  const float* Wih1 = (const float*)d_in[5];
  const float* Whh1 = (const float*)d_in[6];
  const float* bih1 = (const float*)d_in[7];
  const float* bhh1 = (const float*)d_in[8];
  const float* Wl   = (const float*)d_in[9];
  const float* bl   = (const float*)d_in[10];

  const int B = in_sizes[0] / (256 * 3);   // 128

  if (d_ws != nullptr && ws_size >= 8192 * sizeof(uint4)) {
    hipLaunchKernelGGL(wb_prepack, dim3(16), dim3(512), 0, stream,
                       Wih1, (uint4*)d_ws);
    hipLaunchKernelGGL((lstm_roll<1>), dim3(B), dim3(512), 0, stream,
                       traj, Wih0, Whh0, bih0, bhh0, Wih1, Whh1, bih1, bhh1,
                       Wl, bl, (const uint4*)d_ws, (float*)d_out);
  } else {
    hipLaunchKernelGGL((lstm_roll<0>), dim3(B), dim3(512), 0, stream,
                       traj, Wih0, Whh0, bih0, bhh0, Wih1, Whh1, bih1, bhh1,
                       Wl, bl, (const uint4*)nullptr, (float*)d_out);
  }
}